// Round 6
// baseline (417.202 us; speedup 1.0000x reference)
//
#include <hip/hip_runtime.h>

// Problem constants (match reference)
#define T    32768
#define CLS  1024
#define NL   3

// Chunked-scan: 4096 chunks of 8 steps, 32-step warm-up, layer-skewed
// pipeline, x-window in registers, fully unrolled. __launch_bounds__(64,1)
// is REQUIRED: without it the backend budgets ~48 VGPRs and spills the
// x-window + weights to scratch (R4: 85us; ~4900 cyc/iter of L2 scratch
// traffic). WARM=32 bit-exact (R4/R5 absmax 0.0).
// Session context: dur_us floor ~185us is harness restore (512MiB d_ws
// re-poison fill at 77us/dispatch + 128MiB lin_w copy); controllable tail
// is lstm (~5us) + linear (~25us, BW floor 20.3) + softmax + launches.
#define CH     8
#define NCHUNK (T / CH)            // 4096 lanes = 64 wave64 blocks
#define WARM   32
#define SITER  (WARM + CH + 2)     // 42 (incl. 2-deep pipeline skew)
#define NX     (SITER - 2)         // 40 x values consumed by layer 0

#define LOG2E 1.4426950408889634f

__device__ __forceinline__ float rcp_f(float x) { return __builtin_amdgcn_rcpf(x); }

// One LSTM layer-step, pre-scaled math:
//  sigmoid(p) = rcp(1+exp2(p'))   (-log2e folded into weights)
//  tanh(p)    = 1-2*rcp(1+exp2(p')) (+2log2e folded into weights)
//  cell kept pre-scaled C = 2log2e*c so tanh(c) needs no extra mul.
//  ph[] = wh'*h + bb' is the layer's carried state.
__device__ __forceinline__ float lstm_step(
    float inp, const float (&wi)[4], const float (&wh)[4],
    const float (&bb)[4], float& C, float (&ph)[4])
{
    float pi = fmaf(wi[0], inp, ph[0]);
    float pf = fmaf(wi[1], inp, ph[1]);
    float pg = fmaf(wi[2], inp, ph[2]);
    float po = fmaf(wi[3], inp, ph[3]);
    float ri = rcp_f(1.0f + __builtin_exp2f(pi));
    float rf = rcp_f(1.0f + __builtin_exp2f(pf));
    float rg = rcp_f(1.0f + __builtin_exp2f(pg));
    float ro = rcp_f(1.0f + __builtin_exp2f(po));
    float g  = fmaf(-2.0f, rg, 1.0f);          // tanh(pre_g)
    float i2 = (2.0f * LOG2E) * ri;
    float Cn = fmaf(rf, C, i2 * g);            // scaled cell
    float rc = rcp_f(1.0f + __builtin_exp2f(Cn));
    float hn = fmaf(-2.0f * ro, rc, ro);       // o * tanh(c)
    C = Cn;
    ph[0] = fmaf(wh[0], hn, bb[0]);
    ph[1] = fmaf(wh[1], hn, bb[1]);
    ph[2] = fmaf(wh[2], hn, bb[2]);
    ph[3] = fmaf(wh[3], hn, bb[3]);
    return hn;
}

__global__ void __launch_bounds__(64, 1) lstm_scan(
    const float* __restrict__ x,   const float* __restrict__ h0,
    const float* __restrict__ c0,  const float* __restrict__ w_ih,
    const float* __restrict__ w_hh,const float* __restrict__ b_ih,
    const float* __restrict__ b_hh,float* __restrict__ outs,
    float* __restrict__ logits,    int* __restrict__ counter)
{
    // block 0 zeroes logits + arrival counter for the fused linear stage
    if (blockIdx.x == 0) {
#pragma unroll
        for (int k = 0; k < CLS / 64; ++k) logits[threadIdx.x + 64 * k] = 0.0f;
        if (threadIdx.x == 0) *counter = 0;
    }

    const int lane = blockIdx.x * 64 + threadIdx.x;   // chunk id
    const int base = lane * CH;
    int t0 = base - WARM;
    const bool exact = (t0 <= 0);   // start at t=0 with true (h0,c0)
    if (t0 < 0) t0 = 0;
    const int rel0 = t0 - base - 2; // store predicate: rel = s + rel0 in [0,CH)
    float* __restrict__ ob = outs + base;

    // ---- preload the lane's entire x window into registers ----
    // t0 is a multiple of 8 => 32B-aligned; t0+NX-1 <= T-1 for all lanes.
    float xr[NX];
    {
        const float4* __restrict__ xv = (const float4*)(x + t0);
#pragma unroll
        for (int i = 0; i < NX / 4; ++i) {
            float4 v = xv[i];
            xr[4 * i + 0] = v.x;  xr[4 * i + 1] = v.y;
            xr[4 * i + 2] = v.z;  xr[4 * i + 3] = v.w;
        }
    }

    // gate scales: i,f,o -> -log2e (sigmoid); g -> +2log2e (tanh)
    float wi2[NL][4], wh2[NL][4], bb2[NL][4], ph[NL][4];
    float C[NL];
#pragma unroll
    for (int l = 0; l < NL; ++l) {
        const float s[4] = {-LOG2E, -LOG2E, 2.0f * LOG2E, -LOG2E};
#pragma unroll
        for (int k = 0; k < 4; ++k) {
            wi2[l][k] = s[k] * w_ih[l * 4 + k];
            wh2[l][k] = s[k] * w_hh[l * 4 + k];
            bb2[l][k] = s[k] * (b_ih[l * 4 + k] + b_hh[l * 4 + k]);
        }
        float hi = exact ? h0[l] : 0.0f;
        C[l] = exact ? (2.0f * LOG2E) * c0[l] : 0.0f;
#pragma unroll
        for (int k = 0; k < 4; ++k) ph[l][k] = fmaf(wh2[l][k], hi, bb2[l][k]);
    }

    // ---- layer-skewed pipeline: at iter s, L0@t0+s, L1@t0+s-1, L2@t0+s-2
    float in1 = lstm_step(xr[0], wi2[0], wh2[0], bb2[0], C[0], ph[0]);
    float in2;
    {
        float n0 = lstm_step(xr[1], wi2[0], wh2[0], bb2[0], C[0], ph[0]);
        float n1 = lstm_step(in1,   wi2[1], wh2[1], bb2[1], C[1], ph[1]);
        in1 = n0;  in2 = n1;
    }
#pragma unroll
    for (int s = 2; s < SITER - 2; ++s) {       // s = 2..39, consumes xr[s]
        float n0 = lstm_step(xr[s], wi2[0], wh2[0], bb2[0], C[0], ph[0]);
        float n1 = lstm_step(in1,   wi2[1], wh2[1], bb2[1], C[1], ph[1]);
        float n2 = lstm_step(in2,   wi2[2], wh2[2], bb2[2], C[2], ph[2]);
        int rel = s + rel0;
        if ((unsigned)rel < CH) ob[rel] = n2;
        in1 = n0;  in2 = n1;
    }
    {   // epilogue s = SITER-2: L1, L2
        float n1 = lstm_step(in1, wi2[1], wh2[1], bb2[1], C[1], ph[1]);
        float n2 = lstm_step(in2, wi2[2], wh2[2], bb2[2], C[2], ph[2]);
        int rel = (SITER - 2) + rel0;
        if ((unsigned)rel < CH) ob[rel] = n2;
        in2 = n1;
    }
    {   // epilogue s = SITER-1: L2 only
        float n2 = lstm_step(in2, wi2[2], wh2[2], bb2[2], C[2], ph[2]);
        int rel = (SITER - 1) + rel0;
        if ((unsigned)rel < CH) ob[rel] = n2;
    }
}

// Fused linear + softmax. 4096 blocks: row = bid>>2, seg = bid&3; each
// block dots an 8192-elem segment (32 KiB of lin_w), atomically adds its
// partial (+bias for seg 0) to logits[row], then the LAST block to arrive
// (device-scope counter) performs the softmax inline, reading logits via
// atomicAdd(p, 0.0f) for guaranteed device-scope visibility.
__global__ void __launch_bounds__(256, 2) linear_softmax(
    const float* __restrict__ outs, const float* __restrict__ lin_w,
    const float* __restrict__ lin_b, float* __restrict__ logits,
    int* __restrict__ counter, float* __restrict__ out)
{
    __shared__ float red[4];
    __shared__ int   s_last;
    const int row = blockIdx.x >> 2;
    const int seg = blockIdx.x & 3;
    const float4* __restrict__ wr = (const float4*)(lin_w + (size_t)row * T + seg * 8192);
    const float4* __restrict__ ov = (const float4*)(outs + seg * 8192);

    float a0 = 0.f, a1 = 0.f;
    const int i = threadIdx.x;
    float4 w0 = wr[i];         float4 o0 = ov[i];
    float4 w1 = wr[i + 256];   float4 o1 = ov[i + 256];
    float4 w2 = wr[i + 512];   float4 o2 = ov[i + 512];
    float4 w3 = wr[i + 768];   float4 o3 = ov[i + 768];
    float4 w4 = wr[i + 1024];  float4 o4 = ov[i + 1024];
    float4 w5 = wr[i + 1280];  float4 o5 = ov[i + 1280];
    float4 w6 = wr[i + 1536];  float4 o6 = ov[i + 1536];
    float4 w7 = wr[i + 1792];  float4 o7 = ov[i + 1792];
    a0 = fmaf(w0.x,o0.x,a0); a0 = fmaf(w0.y,o0.y,a0); a0 = fmaf(w0.z,o0.z,a0); a0 = fmaf(w0.w,o0.w,a0);
    a1 = fmaf(w1.x,o1.x,a1); a1 = fmaf(w1.y,o1.y,a1); a1 = fmaf(w1.z,o1.z,a1); a1 = fmaf(w1.w,o1.w,a1);
    a0 = fmaf(w2.x,o2.x,a0); a0 = fmaf(w2.y,o2.y,a0); a0 = fmaf(w2.z,o2.z,a0); a0 = fmaf(w2.w,o2.w,a0);
    a1 = fmaf(w3.x,o3.x,a1); a1 = fmaf(w3.y,o3.y,a1); a1 = fmaf(w3.z,o3.z,a1); a1 = fmaf(w3.w,o3.w,a1);
    a0 = fmaf(w4.x,o4.x,a0); a0 = fmaf(w4.y,o4.y,a0); a0 = fmaf(w4.z,o4.z,a0); a0 = fmaf(w4.w,o4.w,a0);
    a1 = fmaf(w5.x,o5.x,a1); a1 = fmaf(w5.y,o5.y,a1); a1 = fmaf(w5.z,o5.z,a1); a1 = fmaf(w5.w,o5.w,a1);
    a0 = fmaf(w6.x,o6.x,a0); a0 = fmaf(w6.y,o6.y,a0); a0 = fmaf(w6.z,o6.z,a0); a0 = fmaf(w6.w,o6.w,a0);
    a1 = fmaf(w7.x,o7.x,a1); a1 = fmaf(w7.y,o7.y,a1); a1 = fmaf(w7.z,o7.z,a1); a1 = fmaf(w7.w,o7.w,a1);

    float acc = a0 + a1;
#pragma unroll
    for (int off = 32; off > 0; off >>= 1) acc += __shfl_down(acc, off, 64);
    if ((threadIdx.x & 63) == 0) red[threadIdx.x >> 6] = acc;
    __syncthreads();
    if (threadIdx.x == 0) {
        float p = (red[0] + red[1]) + (red[2] + red[3]);
        if (seg == 0) p += lin_b[row];
        atomicAdd(&logits[row], p);
        __threadfence();                         // release our add
        int ticket = atomicAdd(counter, 1);
        s_last = (ticket == 4 * CLS - 1);
    }
    __syncthreads();
    if (!s_last) return;

    // ---- last block: softmax over the 1024 completed logits ----
    __shared__ float sm_max[4];
    __shared__ float sm_sum[4];
    const int tid  = threadIdx.x;
    const int wave = tid >> 6;

    // device-scope reads (atomic RMW with 0 returns current value)
    float v0 = atomicAdd(&logits[tid],       0.0f);
    float v1 = atomicAdd(&logits[tid + 256], 0.0f);
    float v2 = atomicAdd(&logits[tid + 512], 0.0f);
    float v3 = atomicAdd(&logits[tid + 768], 0.0f);

    float m = fmaxf(fmaxf(v0, v1), fmaxf(v2, v3));
#pragma unroll
    for (int off = 32; off > 0; off >>= 1) m = fmaxf(m, __shfl_down(m, off, 64));
    if ((tid & 63) == 0) sm_max[wave] = m;
    __syncthreads();
    const float bm = fmaxf(fmaxf(sm_max[0], sm_max[1]), fmaxf(sm_max[2], sm_max[3]));

    float e0 = __expf(v0 - bm);
    float e1 = __expf(v1 - bm);
    float e2 = __expf(v2 - bm);
    float e3 = __expf(v3 - bm);
    float ssum = e0 + e1 + e2 + e3;
#pragma unroll
    for (int off = 32; off > 0; off >>= 1) ssum += __shfl_down(ssum, off, 64);
    if ((tid & 63) == 0) sm_sum[wave] = ssum;
    __syncthreads();
    const float tot = sm_sum[0] + sm_sum[1] + sm_sum[2] + sm_sum[3];
    const float r = 1.0f / tot;

    out[tid]       = e0 * r;
    out[tid + 256] = e1 * r;
    out[tid + 512] = e2 * r;
    out[tid + 768] = e3 * r;
}

extern "C" void kernel_launch(void* const* d_in, const int* in_sizes, int n_in,
                              void* d_out, int out_size, void* d_ws, size_t ws_size,
                              hipStream_t stream) {
    const float* x     = (const float*)d_in[0];
    const float* h0    = (const float*)d_in[1];
    const float* c0    = (const float*)d_in[2];
    const float* w_ih  = (const float*)d_in[3];
    const float* w_hh  = (const float*)d_in[4];
    const float* b_ih  = (const float*)d_in[5];
    const float* b_hh  = (const float*)d_in[6];
    const float* lin_w = (const float*)d_in[7];
    const float* lin_b = (const float*)d_in[8];

    float* outs    = (float*)d_ws;        // T floats
    float* logits  = outs + T;            // CLS floats (zeroed by lstm blk0)
    int*   counter = (int*)(logits + CLS);// arrival counter (zeroed by lstm blk0)
    float* outp    = (float*)d_out;       // CLS floats (softmax probs)

    lstm_scan<<<NCHUNK / 64, 64, 0, stream>>>(x, h0, c0, w_ih, w_hh, b_ih, b_hh,
                                              outs, logits, counter);
    linear_softmax<<<CLS * 4, 256, 0, stream>>>(outs, lin_w, lin_b, logits,
                                                counter, outp);
}

// Round 7
// 220.201 us; speedup vs baseline: 1.8946x; 1.8946x over previous
//
#include <hip/hip_runtime.h>

// Problem constants (match reference)
#define T    32768
#define CLS  1024
#define NL   3

// Chunked-scan: 4096 chunks of 8 steps, 32-step warm-up, layer-skewed
// pipeline, x-window in registers, fully unrolled. __launch_bounds__(64,1)
// is REQUIRED: without it the backend budgets ~48 VGPRs and spills the
// x-window + weights to scratch (R4: 85us; ~4900 cyc/iter of L2 scratch
// traffic). WARM=32 bit-exact (R4/R5 absmax 0.0).
// R6 lesson: do NOT fuse softmax into the linear via counter+threadfence —
// the fence/atomic tail made the compiler drop to VGPR=32 and serialize the
// 16-deep load batch (250us, VALUBusy 1%). Separate kernels are 10x faster.
// Session context: dur_us floor ~188us is harness restore (512MiB d_ws
// re-poison fill at 77us + 128MiB lin_w restore + small restores/gaps);
// controllable tail ~32us: lstm ~5 + linear ~22 (BW floor 20.3) + softmax ~3.
#define CH     8
#define NCHUNK (T / CH)            // 4096 lanes = 64 wave64 blocks
#define WARM   32
#define SITER  (WARM + CH + 2)     // 42 (incl. 2-deep pipeline skew)
#define NX     (SITER - 2)         // 40 x values consumed by layer 0

#define LOG2E 1.4426950408889634f

__device__ __forceinline__ float rcp_f(float x) { return __builtin_amdgcn_rcpf(x); }

// One LSTM layer-step, pre-scaled math:
//  sigmoid(p) = rcp(1+exp2(p'))   (-log2e folded into weights)
//  tanh(p)    = 1-2*rcp(1+exp2(p')) (+2log2e folded into weights)
//  cell kept pre-scaled C = 2log2e*c so tanh(c) needs no extra mul.
//  ph[] = wh'*h + bb' is the layer's carried state.
__device__ __forceinline__ float lstm_step(
    float inp, const float (&wi)[4], const float (&wh)[4],
    const float (&bb)[4], float& C, float (&ph)[4])
{
    float pi = fmaf(wi[0], inp, ph[0]);
    float pf = fmaf(wi[1], inp, ph[1]);
    float pg = fmaf(wi[2], inp, ph[2]);
    float po = fmaf(wi[3], inp, ph[3]);
    float ri = rcp_f(1.0f + __builtin_exp2f(pi));
    float rf = rcp_f(1.0f + __builtin_exp2f(pf));
    float rg = rcp_f(1.0f + __builtin_exp2f(pg));
    float ro = rcp_f(1.0f + __builtin_exp2f(po));
    float g  = fmaf(-2.0f, rg, 1.0f);          // tanh(pre_g)
    float i2 = (2.0f * LOG2E) * ri;
    float Cn = fmaf(rf, C, i2 * g);            // scaled cell
    float rc = rcp_f(1.0f + __builtin_exp2f(Cn));
    float hn = fmaf(-2.0f * ro, rc, ro);       // o * tanh(c)
    C = Cn;
    ph[0] = fmaf(wh[0], hn, bb[0]);
    ph[1] = fmaf(wh[1], hn, bb[1]);
    ph[2] = fmaf(wh[2], hn, bb[2]);
    ph[3] = fmaf(wh[3], hn, bb[3]);
    return hn;
}

__global__ void __launch_bounds__(64, 1) lstm_scan(
    const float* __restrict__ x,   const float* __restrict__ h0,
    const float* __restrict__ c0,  const float* __restrict__ w_ih,
    const float* __restrict__ w_hh,const float* __restrict__ b_ih,
    const float* __restrict__ b_hh,float* __restrict__ outs,
    float* __restrict__ logits)
{
    // block 0 zeroes logits for the atomic linear stage
    if (blockIdx.x == 0) {
#pragma unroll
        for (int k = 0; k < CLS / 64; ++k) logits[threadIdx.x + 64 * k] = 0.0f;
    }

    const int lane = blockIdx.x * 64 + threadIdx.x;   // chunk id
    const int base = lane * CH;
    int t0 = base - WARM;
    const bool exact = (t0 <= 0);   // start at t=0 with true (h0,c0)
    if (t0 < 0) t0 = 0;
    const int rel0 = t0 - base - 2; // store predicate: rel = s + rel0 in [0,CH)
    float* __restrict__ ob = outs + base;

    // ---- preload the lane's entire x window into registers ----
    // t0 is a multiple of 8 => 32B-aligned; t0+NX-1 <= T-1 for all lanes.
    float xr[NX];
    {
        const float4* __restrict__ xv = (const float4*)(x + t0);
#pragma unroll
        for (int i = 0; i < NX / 4; ++i) {
            float4 v = xv[i];
            xr[4 * i + 0] = v.x;  xr[4 * i + 1] = v.y;
            xr[4 * i + 2] = v.z;  xr[4 * i + 3] = v.w;
        }
    }

    // gate scales: i,f,o -> -log2e (sigmoid); g -> +2log2e (tanh)
    float wi2[NL][4], wh2[NL][4], bb2[NL][4], ph[NL][4];
    float C[NL];
#pragma unroll
    for (int l = 0; l < NL; ++l) {
        const float s[4] = {-LOG2E, -LOG2E, 2.0f * LOG2E, -LOG2E};
#pragma unroll
        for (int k = 0; k < 4; ++k) {
            wi2[l][k] = s[k] * w_ih[l * 4 + k];
            wh2[l][k] = s[k] * w_hh[l * 4 + k];
            bb2[l][k] = s[k] * (b_ih[l * 4 + k] + b_hh[l * 4 + k]);
        }
        float hi = exact ? h0[l] : 0.0f;
        C[l] = exact ? (2.0f * LOG2E) * c0[l] : 0.0f;
#pragma unroll
        for (int k = 0; k < 4; ++k) ph[l][k] = fmaf(wh2[l][k], hi, bb2[l][k]);
    }

    // ---- layer-skewed pipeline: at iter s, L0@t0+s, L1@t0+s-1, L2@t0+s-2
    float in1 = lstm_step(xr[0], wi2[0], wh2[0], bb2[0], C[0], ph[0]);
    float in2;
    {
        float n0 = lstm_step(xr[1], wi2[0], wh2[0], bb2[0], C[0], ph[0]);
        float n1 = lstm_step(in1,   wi2[1], wh2[1], bb2[1], C[1], ph[1]);
        in1 = n0;  in2 = n1;
    }
#pragma unroll
    for (int s = 2; s < SITER - 2; ++s) {       // s = 2..39, consumes xr[s]
        float n0 = lstm_step(xr[s], wi2[0], wh2[0], bb2[0], C[0], ph[0]);
        float n1 = lstm_step(in1,   wi2[1], wh2[1], bb2[1], C[1], ph[1]);
        float n2 = lstm_step(in2,   wi2[2], wh2[2], bb2[2], C[2], ph[2]);
        int rel = s + rel0;
        if ((unsigned)rel < CH) ob[rel] = n2;
        in1 = n0;  in2 = n1;
    }
    {   // epilogue s = SITER-2: L1, L2
        float n1 = lstm_step(in1, wi2[1], wh2[1], bb2[1], C[1], ph[1]);
        float n2 = lstm_step(in2, wi2[2], wh2[2], bb2[2], C[2], ph[2]);
        int rel = (SITER - 2) + rel0;
        if ((unsigned)rel < CH) ob[rel] = n2;
        in2 = n1;
    }
    {   // epilogue s = SITER-1: L2 only
        float n2 = lstm_step(in2, wi2[2], wh2[2], bb2[2], C[2], ph[2]);
        int rel = (SITER - 1) + rel0;
        if ((unsigned)rel < CH) ob[rel] = n2;
    }
}

// 4096 blocks: row = bid>>2, seg = bid&3; each block dots an 8192-elem
// segment (32 KiB of lin_w) and atomically adds its partial to logits[row].
// (256,2): VGPR budget so the 16 in-flight float4 loads never spill.
__global__ void __launch_bounds__(256, 2) linear_partial(
    const float* __restrict__ outs, const float* __restrict__ lin_w,
    float* __restrict__ logits)
{
    __shared__ float red[4];
    const int row = blockIdx.x >> 2;
    const int seg = blockIdx.x & 3;
    const float4* __restrict__ wr = (const float4*)(lin_w + (size_t)row * T + seg * 8192);
    const float4* __restrict__ ov = (const float4*)(outs + seg * 8192);

    float a0 = 0.f, a1 = 0.f;
    const int i = threadIdx.x;
    float4 w0 = wr[i];         float4 o0 = ov[i];
    float4 w1 = wr[i + 256];   float4 o1 = ov[i + 256];
    float4 w2 = wr[i + 512];   float4 o2 = ov[i + 512];
    float4 w3 = wr[i + 768];   float4 o3 = ov[i + 768];
    float4 w4 = wr[i + 1024];  float4 o4 = ov[i + 1024];
    float4 w5 = wr[i + 1280];  float4 o5 = ov[i + 1280];
    float4 w6 = wr[i + 1536];  float4 o6 = ov[i + 1536];
    float4 w7 = wr[i + 1792];  float4 o7 = ov[i + 1792];
    a0 = fmaf(w0.x,o0.x,a0); a0 = fmaf(w0.y,o0.y,a0); a0 = fmaf(w0.z,o0.z,a0); a0 = fmaf(w0.w,o0.w,a0);
    a1 = fmaf(w1.x,o1.x,a1); a1 = fmaf(w1.y,o1.y,a1); a1 = fmaf(w1.z,o1.z,a1); a1 = fmaf(w1.w,o1.w,a1);
    a0 = fmaf(w2.x,o2.x,a0); a0 = fmaf(w2.y,o2.y,a0); a0 = fmaf(w2.z,o2.z,a0); a0 = fmaf(w2.w,o2.w,a0);
    a1 = fmaf(w3.x,o3.x,a1); a1 = fmaf(w3.y,o3.y,a1); a1 = fmaf(w3.z,o3.z,a1); a1 = fmaf(w3.w,o3.w,a1);
    a0 = fmaf(w4.x,o4.x,a0); a0 = fmaf(w4.y,o4.y,a0); a0 = fmaf(w4.z,o4.z,a0); a0 = fmaf(w4.w,o4.w,a0);
    a1 = fmaf(w5.x,o5.x,a1); a1 = fmaf(w5.y,o5.y,a1); a1 = fmaf(w5.z,o5.z,a1); a1 = fmaf(w5.w,o5.w,a1);
    a0 = fmaf(w6.x,o6.x,a0); a0 = fmaf(w6.y,o6.y,a0); a0 = fmaf(w6.z,o6.z,a0); a0 = fmaf(w6.w,o6.w,a0);
    a1 = fmaf(w7.x,o7.x,a1); a1 = fmaf(w7.y,o7.y,a1); a1 = fmaf(w7.z,o7.z,a1); a1 = fmaf(w7.w,o7.w,a1);

    float acc = a0 + a1;
#pragma unroll
    for (int off = 32; off > 0; off >>= 1) acc += __shfl_down(acc, off, 64);
    if ((threadIdx.x & 63) == 0) red[threadIdx.x >> 6] = acc;
    __syncthreads();
    if (threadIdx.x == 0) {
        atomicAdd(&logits[row], (red[0] + red[1]) + (red[2] + red[3]));
    }
}

// softmax over 1024 logits (+bias); single block, 256 threads x 4
__global__ void __launch_bounds__(256) softmax1024(
    const float* __restrict__ logits, const float* __restrict__ lin_b,
    float* __restrict__ out)
{
    __shared__ float sm_max[4];
    __shared__ float sm_sum[4];
    const int tid  = threadIdx.x;
    const int wave = tid >> 6;

    float v0 = logits[tid]       + lin_b[tid];
    float v1 = logits[tid + 256] + lin_b[tid + 256];
    float v2 = logits[tid + 512] + lin_b[tid + 512];
    float v3 = logits[tid + 768] + lin_b[tid + 768];

    float m = fmaxf(fmaxf(v0, v1), fmaxf(v2, v3));
#pragma unroll
    for (int off = 32; off > 0; off >>= 1) m = fmaxf(m, __shfl_down(m, off, 64));
    if ((tid & 63) == 0) sm_max[wave] = m;
    __syncthreads();
    const float bm = fmaxf(fmaxf(sm_max[0], sm_max[1]), fmaxf(sm_max[2], sm_max[3]));

    float e0 = __expf(v0 - bm);
    float e1 = __expf(v1 - bm);
    float e2 = __expf(v2 - bm);
    float e3 = __expf(v3 - bm);
    float ssum = e0 + e1 + e2 + e3;
#pragma unroll
    for (int off = 32; off > 0; off >>= 1) ssum += __shfl_down(ssum, off, 64);
    if ((tid & 63) == 0) sm_sum[wave] = ssum;
    __syncthreads();
    const float tot = sm_sum[0] + sm_sum[1] + sm_sum[2] + sm_sum[3];
    const float r = 1.0f / tot;

    out[tid]       = e0 * r;
    out[tid + 256] = e1 * r;
    out[tid + 512] = e2 * r;
    out[tid + 768] = e3 * r;
}

extern "C" void kernel_launch(void* const* d_in, const int* in_sizes, int n_in,
                              void* d_out, int out_size, void* d_ws, size_t ws_size,
                              hipStream_t stream) {
    const float* x     = (const float*)d_in[0];
    const float* h0    = (const float*)d_in[1];
    const float* c0    = (const float*)d_in[2];
    const float* w_ih  = (const float*)d_in[3];
    const float* w_hh  = (const float*)d_in[4];
    const float* b_ih  = (const float*)d_in[5];
    const float* b_hh  = (const float*)d_in[6];
    const float* lin_w = (const float*)d_in[7];
    const float* lin_b = (const float*)d_in[8];

    float* outs   = (float*)d_ws;        // T floats
    float* logits = outs + T;            // CLS floats (zeroed by lstm blk0)
    float* outp   = (float*)d_out;       // CLS floats (softmax probs)

    lstm_scan<<<NCHUNK / 64, 64, 0, stream>>>(x, h0, c0, w_ih, w_hh, b_ih, b_hh,
                                              outs, logits);
    linear_partial<<<CLS * 4, 256, 0, stream>>>(outs, lin_w, logits);
    softmax1024<<<1, 256, 0, stream>>>(logits, lin_b, outp);
}